// Round 1
// 376.893 us; speedup vs baseline: 1.0642x; 1.0642x over previous
//
#include <hip/hip_runtime.h>

// Problem constants
// B=32, C=273, T=4096, CHOUT=270, D=242 (11x11 freqs x {cos,sin})
#define NB 32
#define NC 273
#define NT 4096
#define NO 270
#define ND 242
#define OPAD 288  // padded output-channel count (multiple of 16, >= 270)
#define CPAD 288  // padded channel (K) count (multiple of 32, >= 273)
#define TBLK 64   // t columns per einsum block

typedef __attribute__((ext_vector_type(8))) short short8;
typedef __attribute__((ext_vector_type(4))) float f32x4;

__device__ __forceinline__ short f2bf(float f) {
    union { float f; unsigned int u; } x;
    x.f = f;
    unsigned int r = x.u + 0x7fffu + ((x.u >> 16) & 1u);  // RNE (no NaN/inf in data)
    return (short)(r >> 16);
}

// ---------------------------------------------------------------------------
// Kernel 1: Fourier embedding. emb[b*273+c][242]: cos at [idx], sin at [121+idx]
// ---------------------------------------------------------------------------
__global__ void emb_kernel(const float* __restrict__ pos, float* __restrict__ emb) {
    const int g = blockIdx.x * 256 + threadIdx.x;
    const int TOT = NB * NC * 121;  // 1,057,056
    if (g >= TOT) return;
    const int p = g / 121;
    const int idx = g - p * 121;
    const int fi = idx / 11;
    const int fj = idx - fi * 11;
    const float scale = 4.487989505128276f;  // 2*pi/1.4
    const float px = pos[p * 2] + 0.2f;
    const float py = pos[p * 2 + 1] + 0.2f;
    const float loc = px * (scale * (float)fi) + py * (scale * (float)fj);
    emb[(size_t)p * ND + idx] = cosf(loc);
    emb[(size_t)p * ND + 121 + idx] = sinf(loc);
}

// ---------------------------------------------------------------------------
// Kernel 2: scores[b][o][c] = sum_d heads[subj[b]][o][d]*emb[b][c][d] + offset
// fp32 tiled GEMM, 32x64 tile (grid 1440 = 5.6 blocks/CU, small LDS -> high
// occupancy so staging latency is hidden by TLP). Kchunk=16.
// ---------------------------------------------------------------------------
__global__ __launch_bounds__(256) void scores_kernel(
    const float* __restrict__ emb, const float* __restrict__ heads,
    const int* __restrict__ subj, const float* __restrict__ pos,
    float* __restrict__ scores) {
    __shared__ float As[16 * 36];  // As[k][i] = heads[s][o0+i][kc+k], 32 rows +4 pad
    __shared__ float Bs[16 * 68];  // Bs[k][j] = emb[b][c0+j][kc+k], 64 rows +4 pad
    const int b = blockIdx.z;
    const int o0 = blockIdx.y * 32;
    const int c0 = blockIdx.x * 64;
    const int tid = threadIdx.x;
    const int s = subj[b];
    const int tx = tid & 15, ty = tid >> 4;  // ty 0..15
    const int srow = tid >> 3;  // 0..31
    const int sfp = tid & 7;    // float2 index: cols sfp*2, sfp*2+1

    float acc[2][4] = {};

    for (int kc = 0; kc < 256; kc += 16) {
        const int d = kc + sfp * 2;  // even; ND even -> never a partial pair
        // A: 32 rows x 16 k
        {
            const int o = o0 + srow;
            float2 av = make_float2(0.f, 0.f);
            if (d < ND && o < NO)
                av = *reinterpret_cast<const float2*>(
                    &heads[((size_t)(s * NO + o)) * ND + d]);
            As[(sfp * 2 + 0) * 36 + srow] = av.x;
            As[(sfp * 2 + 1) * 36 + srow] = av.y;
        }
        // B: 64 rows x 16 k
#pragma unroll
        for (int half = 0; half < 2; ++half) {
            const int row = srow + half * 32;
            const int c = c0 + row;
            float2 bv = make_float2(0.f, 0.f);
            if (d < ND && c < NC)
                bv = *reinterpret_cast<const float2*>(
                    &emb[((size_t)(b * NC + c)) * ND + d]);
            Bs[(sfp * 2 + 0) * 68 + row] = bv.x;
            Bs[(sfp * 2 + 1) * 68 + row] = bv.y;
        }
        __syncthreads();
#pragma unroll
        for (int k = 0; k < 16; ++k) {
            const float2 a = *reinterpret_cast<const float2*>(&As[k * 36 + ty * 2]);
            const float4 bvv = *reinterpret_cast<const float4*>(&Bs[k * 68 + tx * 4]);
            const float aa[2] = {a.x, a.y};
            const float bb[4] = {bvv.x, bvv.y, bvv.z, bvv.w};
#pragma unroll
            for (int ii = 0; ii < 2; ++ii)
#pragma unroll
                for (int jj = 0; jj < 4; ++jj) acc[ii][jj] += aa[ii] * bb[jj];
        }
        __syncthreads();
    }

#pragma unroll
    for (int ii = 0; ii < 2; ++ii) {
        const int o = o0 + ty * 2 + ii;
        if (o >= NO) continue;
#pragma unroll
        for (int jj = 0; jj < 4; ++jj) {
            const int c = c0 + tx * 4 + jj;
            if (c >= NC) continue;
            const float px = pos[((size_t)(b * NC + c)) * 2];
            const float py = pos[((size_t)(b * NC + c)) * 2 + 1];
            const float off = (px == -0.1f && py == -0.1f) ? -1e9f : 0.0f;
            scores[((size_t)(b * NO + o)) * NC + c] = acc[ii][jj] + off;
        }
    }
}

// ---------------------------------------------------------------------------
// Kernel 3: softmax over channels (273) -> bf16 weights wbf[b][OPAD][CPAD].
// One wave per (b,o) row. Rows o>=270 and cols c>=273 are zero-filled so the
// einsum can run on the padded 288x288 tile with no masking.
// ---------------------------------------------------------------------------
__global__ __launch_bounds__(64) void softmax_kernel(
    const float* __restrict__ scores, short* __restrict__ wbf) {
    const int row = blockIdx.x;           // b*OPAD + o
    const int b = row / OPAD;
    const int o = row - b * OPAD;
    short* w = wbf + (size_t)row * CPAD;
    const int lane = threadIdx.x;

    if (o >= NO) {  // zero padding rows
        for (int c = lane; c < CPAD; c += 64) w[c] = 0;
        return;
    }

    const float* s = scores + ((size_t)(b * NO + o)) * NC;
    float v[5];
    int cnt = 0;
    float mx = -1e30f;
    for (int c = lane; c < NC; c += 64) {
        v[cnt] = s[c];
        mx = fmaxf(mx, v[cnt]);
        ++cnt;
    }
#pragma unroll
    for (int off = 32; off; off >>= 1) mx = fmaxf(mx, __shfl_xor(mx, off));
    float sum = 0.0f;
    for (int i = 0; i < cnt; ++i) {
        v[i] = expf(v[i] - mx);
        sum += v[i];
    }
#pragma unroll
    for (int off = 32; off; off >>= 1) sum += __shfl_xor(sum, off);
    const float inv = 1.0f / sum;
    int i = 0;
    for (int c = lane; c < CPAD; c += 64) {
        float val = 0.0f;
        if (c < NC) val = v[i++] * inv;
        w[c] = f2bf(val);
    }
}

// ---------------------------------------------------------------------------
// Kernel 4: FUSED transpose+einsum.
// out[b][o][t] = sum_c w[b][o][c] * meg[b][c][t], bf16 MFMA 16x16x32.
// Block: all M=288 (o, padded) x 64 t, so meg is fetched from HBM exactly
// once (no megT intermediate, no 5x o-tile re-reads). B-fragments are built
// in-register from f32 meg (RNE->bf16); A (weights) is re-staged into LDS per
// 32-c K-chunk from the small L2-resident wbf buffer.
// Wave split: 2 (M-half, 144 = 9 frags) x 2 (t-half, 32 = 2 frags);
// acc = 9x2 f32x4 = 72 VGPRs/thread.
// LDS A row stride 40 shorts (80 B): ds_read_b128 bank start =
// (20*row+4q)%32 -> 2 lanes per 4-bank group = conflict-free (m136).
// ---------------------------------------------------------------------------
__global__ __launch_bounds__(256) void einsum_kernel(
    const float* __restrict__ meg, const short* __restrict__ wbf,
    float* __restrict__ out) {
    __shared__ short Alds[OPAD * 40];  // 23040 B
    const int b = blockIdx.z;
    const int t0 = blockIdx.x * TBLK;
    const int tid = threadIdx.x;
    const int l = tid & 63;
    const int wv = tid >> 6;   // 0..3
    const int mw = wv >> 1;    // o-half: rows mw*144 .. mw*144+143
    const int tw = wv & 1;     // t-half: cols tw*32 .. tw*32+31
    const int q = l >> 4;      // 0..3
    const int nlo = l & 15;

    f32x4 acc[9][2];
#pragma unroll
    for (int i = 0; i < 9; ++i)
#pragma unroll
        for (int j = 0; j < 2; ++j) acc[i][j] = {0.f, 0.f, 0.f, 0.f};

    const float* mbase = meg + ((size_t)b * NC) * NT + t0 + tw * 32 + nlo;
    const short* wbase = wbf + ((size_t)b * OPAD) * CPAD;

    for (int kc = 0; kc < CPAD; kc += 32) {
        // ---- B: 16 dword loads straight from meg (f32, [c][t] layout) ----
        // per instr: 4 rows (q) x 16 consecutive t (nlo) = 4 x 64 B segments;
        // nf=0/1 cover adjacent 64 B -> every 128 B line fully consumed.
        float bf0[8], bf1[8];
#pragma unroll
        for (int j = 0; j < 8; ++j) {
            int c = kc + q * 8 + j;
            if (c >= NC) c = 0;  // clamp: A rows are 0 there, product is 0
            const float* mrow = mbase + (size_t)c * NT;
            bf0[j] = mrow[0];
            bf1[j] = mrow[16];
        }
        // ---- A: stage w[0..287][kc..kc+31] bf16 into LDS (16 B segs) ----
        for (int sidx = tid; sidx < OPAD * 4; sidx += 256) {
            const int row = sidx >> 2;
            const int q4 = sidx & 3;
            const short8 v = *reinterpret_cast<const short8*>(
                wbase + (size_t)row * CPAD + kc + q4 * 8);
            *reinterpret_cast<short8*>(&Alds[row * 40 + q4 * 8]) = v;
        }
        __syncthreads();
        // convert B to bf16 fragments (lane holds k = q*8+j, col = nlo)
        short8 b0, b1;
#pragma unroll
        for (int j = 0; j < 8; ++j) {
            b0[j] = f2bf(bf0[j]);
            b1[j] = f2bf(bf1[j]);
        }
#pragma unroll
        for (int mt = 0; mt < 9; ++mt) {
            const short8 av = *reinterpret_cast<const short8*>(
                &Alds[(mw * 144 + mt * 16 + nlo) * 40 + q * 8]);
            acc[mt][0] = __builtin_amdgcn_mfma_f32_16x16x32_bf16(av, b0, acc[mt][0], 0, 0, 0);
            acc[mt][1] = __builtin_amdgcn_mfma_f32_16x16x32_bf16(av, b1, acc[mt][1], 0, 0, 0);
        }
        __syncthreads();
    }

    // ---- store: C/D layout col = nlo (t), row = q*4 + r (o) ----
    const int tcol = t0 + tw * 32 + nlo;
#pragma unroll
    for (int mt = 0; mt < 9; ++mt) {
        const int ob = mw * 144 + mt * 16 + q * 4;
#pragma unroll
        for (int nf = 0; nf < 2; ++nf) {
            const int t = tcol + nf * 16;
#pragma unroll
            for (int r = 0; r < 4; ++r) {
                const int o = ob + r;
                if (o < NO) out[((size_t)(b * NO + o)) * NT + t] = acc[mt][nf][r];
            }
        }
    }
}

// ---------------------------------------------------------------------------
extern "C" void kernel_launch(void* const* d_in, const int* in_sizes, int n_in,
                              void* d_out, int out_size, void* d_ws, size_t ws_size,
                              hipStream_t stream) {
    const float* meg = (const float*)d_in[0];       // [32,273,4096] f32
    const float* pos = (const float*)d_in[1];       // [32,273,2] f32
    const int* subj = (const int*)d_in[2];          // [32] i32
    const float* heads = (const float*)d_in[3];     // [200,270,242] f32
    float* out = (float*)d_out;                     // [32,270,4096] f32

    float* emb = (float*)d_ws;                          // 32*273*242 f32 (8.5 MB)
    float* scores = emb + (size_t)NB * NC * ND;         // 32*270*273 f32 (9.4 MB)
    short* wbf = (short*)(scores + (size_t)NB * NO * NC);  // 32*288*288 bf16 (5.3 MB)

    const int emb_items = NB * NC * 121;
    emb_kernel<<<dim3((emb_items + 255) / 256), dim3(256), 0, stream>>>(pos, emb);
    scores_kernel<<<dim3(5, 9, NB), dim3(256), 0, stream>>>(emb, heads, subj, pos, scores);
    softmax_kernel<<<dim3(NB * OPAD), dim3(64), 0, stream>>>(scores, wbf);
    einsum_kernel<<<dim3(NT / TBLK, 1, NB), dim3(256), 0, stream>>>(meg, wbf, out);
}

// Round 4
// 372.652 us; speedup vs baseline: 1.0763x; 1.0114x over previous
//
#include <hip/hip_runtime.h>

// Problem constants
// B=32, C=273, T=4096, CHOUT=270, D=242 (11x11 freqs x {cos,sin})
#define NB 32
#define NC 273
#define NT 4096
#define NO 270
#define ND 242
#define OPAD 288  // padded output-channel count (multiple of 16, >= 270)
#define CPAD 288  // padded channel (K) count (multiple of 32, >= 273)
#define TBLK 64   // t columns per einsum block

typedef __attribute__((ext_vector_type(8))) short short8;
typedef __attribute__((ext_vector_type(4))) float f32x4;

__device__ __forceinline__ short f2bf(float f) {
    union { float f; unsigned int u; } x;
    x.f = f;
    unsigned int r = x.u + 0x7fffu + ((x.u >> 16) & 1u);  // RNE (no NaN/inf in data)
    return (short)(r >> 16);
}

// ---------------------------------------------------------------------------
// Kernel 1: Fourier embedding. emb[b*273+c][242]: cos at [idx], sin at [121+idx]
// ---------------------------------------------------------------------------
__global__ void emb_kernel(const float* __restrict__ pos, float* __restrict__ emb) {
    const int g = blockIdx.x * 256 + threadIdx.x;
    const int TOT = NB * NC * 121;  // 1,057,056
    if (g >= TOT) return;
    const int p = g / 121;
    const int idx = g - p * 121;
    const int fi = idx / 11;
    const int fj = idx - fi * 11;
    const float scale = 4.487989505128276f;  // 2*pi/1.4
    const float px = pos[p * 2] + 0.2f;
    const float py = pos[p * 2 + 1] + 0.2f;
    const float loc = px * (scale * (float)fi) + py * (scale * (float)fj);
    emb[(size_t)p * ND + idx] = cosf(loc);
    emb[(size_t)p * ND + 121 + idx] = sinf(loc);
}

// ---------------------------------------------------------------------------
// Kernel 2: scores[b][o][c] = sum_d heads[subj[b]][o][d]*emb[b][c][d] + offset
// fp32 tiled GEMM, 32x64 tile (grid 1440 = 5.6 blocks/CU, small LDS -> high
// occupancy so staging latency is hidden by TLP). Kchunk=16.
// ---------------------------------------------------------------------------
__global__ __launch_bounds__(256) void scores_kernel(
    const float* __restrict__ emb, const float* __restrict__ heads,
    const int* __restrict__ subj, const float* __restrict__ pos,
    float* __restrict__ scores) {
    __shared__ float As[16 * 36];  // As[k][i] = heads[s][o0+i][kc+k], 32 rows +4 pad
    __shared__ float Bs[16 * 68];  // Bs[k][j] = emb[b][c0+j][kc+k], 64 rows +4 pad
    const int b = blockIdx.z;
    const int o0 = blockIdx.y * 32;
    const int c0 = blockIdx.x * 64;
    const int tid = threadIdx.x;
    const int s = subj[b];
    const int tx = tid & 15, ty = tid >> 4;  // ty 0..15
    const int srow = tid >> 3;  // 0..31
    const int sfp = tid & 7;    // float2 index: cols sfp*2, sfp*2+1

    float acc[2][4] = {};

    for (int kc = 0; kc < 256; kc += 16) {
        const int d = kc + sfp * 2;  // even; ND even -> never a partial pair
        // A: 32 rows x 16 k
        {
            const int o = o0 + srow;
            float2 av = make_float2(0.f, 0.f);
            if (d < ND && o < NO)
                av = *reinterpret_cast<const float2*>(
                    &heads[((size_t)(s * NO + o)) * ND + d]);
            As[(sfp * 2 + 0) * 36 + srow] = av.x;
            As[(sfp * 2 + 1) * 36 + srow] = av.y;
        }
        // B: 64 rows x 16 k
#pragma unroll
        for (int half = 0; half < 2; ++half) {
            const int row = srow + half * 32;
            const int c = c0 + row;
            float2 bv = make_float2(0.f, 0.f);
            if (d < ND && c < NC)
                bv = *reinterpret_cast<const float2*>(
                    &emb[((size_t)(b * NC + c)) * ND + d]);
            Bs[(sfp * 2 + 0) * 68 + row] = bv.x;
            Bs[(sfp * 2 + 1) * 68 + row] = bv.y;
        }
        __syncthreads();
#pragma unroll
        for (int k = 0; k < 16; ++k) {
            const float2 a = *reinterpret_cast<const float2*>(&As[k * 36 + ty * 2]);
            const float4 bvv = *reinterpret_cast<const float4*>(&Bs[k * 68 + tx * 4]);
            const float aa[2] = {a.x, a.y};
            const float bb[4] = {bvv.x, bvv.y, bvv.z, bvv.w};
#pragma unroll
            for (int ii = 0; ii < 2; ++ii)
#pragma unroll
                for (int jj = 0; jj < 4; ++jj) acc[ii][jj] += aa[ii] * bb[jj];
        }
        __syncthreads();
    }

#pragma unroll
    for (int ii = 0; ii < 2; ++ii) {
        const int o = o0 + ty * 2 + ii;
        if (o >= NO) continue;
#pragma unroll
        for (int jj = 0; jj < 4; ++jj) {
            const int c = c0 + tx * 4 + jj;
            if (c >= NC) continue;
            const float px = pos[((size_t)(b * NC + c)) * 2];
            const float py = pos[((size_t)(b * NC + c)) * 2 + 1];
            const float off = (px == -0.1f && py == -0.1f) ? -1e9f : 0.0f;
            scores[((size_t)(b * NO + o)) * NC + c] = acc[ii][jj] + off;
        }
    }
}

// ---------------------------------------------------------------------------
// Kernel 3: softmax over channels (273) -> bf16 weights wbf[b][OPAD][CPAD].
// One wave per (b,o) row. Rows o>=270 and cols c>=273 are zero-filled so the
// einsum can run on the padded 288x288 tile with no masking.
// ---------------------------------------------------------------------------
__global__ __launch_bounds__(64) void softmax_kernel(
    const float* __restrict__ scores, short* __restrict__ wbf) {
    const int row = blockIdx.x;           // b*OPAD + o
    const int b = row / OPAD;
    const int o = row - b * OPAD;
    short* w = wbf + (size_t)row * CPAD;
    const int lane = threadIdx.x;

    if (o >= NO) {  // zero padding rows
        for (int c = lane; c < CPAD; c += 64) w[c] = 0;
        return;
    }

    const float* s = scores + ((size_t)(b * NO + o)) * NC;
    float v[5];
    int cnt = 0;
    float mx = -1e30f;
    for (int c = lane; c < NC; c += 64) {
        v[cnt] = s[c];
        mx = fmaxf(mx, v[cnt]);
        ++cnt;
    }
#pragma unroll
    for (int off = 32; off; off >>= 1) mx = fmaxf(mx, __shfl_xor(mx, off));
    float sum = 0.0f;
    for (int i = 0; i < cnt; ++i) {
        v[i] = expf(v[i] - mx);
        sum += v[i];
    }
#pragma unroll
    for (int off = 32; off; off >>= 1) sum += __shfl_xor(sum, off);
    const float inv = 1.0f / sum;
    int i = 0;
    for (int c = lane; c < CPAD; c += 64) {
        float val = 0.0f;
        if (c < NC) val = v[i++] * inv;
        w[c] = f2bf(val);
    }
}

// ---------------------------------------------------------------------------
// Kernel 4: FUSED transpose+einsum, pipelined with SAFE barriers.
// out[b][o][t] = sum_c w[b][o][c] * meg[b][c][t], bf16 MFMA 16x16x32.
// Block: all M=288 (o, padded) x 64 t; meg fetched from HBM exactly once.
// K split into 3 iterations of CK=96 (54 MFMA per A-visibility barrier).
// B (meg) is register double-buffered; the loads for iteration it+1 are
// issued immediately AFTER the barrier that starts mma(it), so when the next
// __syncthreads drains vmcnt(0) the loads have had the whole 54-MFMA phase
// to complete -> drain costs ~0. Rounds 2/3 NaN'd because the epilogue
// called mma(2): buffer index OOB on Breg[2] (B2 lives in buffer 0).
// FIXED: epilogue is mma(0).
// Wave split: 2 (M-half, 144 = 9 frags) x 2 (t-half, 32 = 2 frags).
// ---------------------------------------------------------------------------
__global__ __launch_bounds__(256) void einsum_kernel(
    const float* __restrict__ meg, const short* __restrict__ wbf,
    float* __restrict__ out) {
    __shared__ short Alds[3 * 288 * 40];  // 69,120 B: [sub][row][40 shorts]
    const int b = blockIdx.z;
    const int t0 = blockIdx.x * TBLK;
    const int tid = threadIdx.x;
    const int l = tid & 63;
    const int wv = tid >> 6;   // 0..3
    const int mw = wv >> 1;    // o-half: rows mw*144 .. mw*144+143
    const int tw = wv & 1;     // t-half: cols tw*32 .. tw*32+31
    const int q = l >> 4;      // 0..3
    const int nlo = l & 15;

    f32x4 acc[9][2];
#pragma unroll
    for (int i = 0; i < 9; ++i)
#pragma unroll
        for (int j = 0; j < 2; ++j) acc[i][j] = {0.f, 0.f, 0.f, 0.f};

    const float* mbase = meg + ((size_t)b * NC) * NT + t0 + tw * 32 + nlo;
    const short* wbase = wbf + ((size_t)b * OPAD) * CPAD;

    // B register double-buffer: [buf][sub][j][nf] - all indices static.
    float Breg[2][3][8][2];

    // Issue the 48 B dword-loads for K-iteration `it` into buffer `buf`.
    // Per instr the wave touches 4 c-rows x 64 B contiguous t = fully coalesced.
    auto loadB = [&](int buf, int it) {
#pragma unroll
        for (int sub = 0; sub < 3; ++sub)
#pragma unroll
            for (int j = 0; j < 8; ++j) {
                int c = it * 96 + sub * 32 + q * 8 + j;
                if (c >= NC) c = 0;  // clamp: A rows there are 0, product is 0
                const float* mrow = mbase + (size_t)c * NT;
                Breg[buf][sub][j][0] = mrow[0];
                Breg[buf][sub][j][1] = mrow[16];
            }
    };

    // Stage A slice [0..287] x [it*96, it*96+96) bf16 into LDS (16 B segs).
    auto stageA = [&](int it) {
        for (int sidx = tid; sidx < 288 * 12; sidx += 256) {
            const int sub = sidx / 1152;  // 0..2
            const int r = sidx - sub * 1152;
            const int row = r >> 2;
            const int q4 = r & 3;
            const short8 v = *reinterpret_cast<const short8*>(
                wbase + (size_t)row * CPAD + it * 96 + sub * 32 + q4 * 8);
            *reinterpret_cast<short8*>(&Alds[(sub * 288 + row) * 40 + q4 * 8]) = v;
        }
    };

    // 54 MFMA on buffer `buf` (MUST be 0 or 1) against the A slice in LDS.
    auto mma = [&](int buf) {
#pragma unroll
        for (int sub = 0; sub < 3; ++sub) {
            short8 b0, b1;
#pragma unroll
            for (int j = 0; j < 8; ++j) {
                b0[j] = f2bf(Breg[buf][sub][j][0]);
                b1[j] = f2bf(Breg[buf][sub][j][1]);
            }
#pragma unroll
            for (int mt = 0; mt < 9; ++mt) {
                const short8 av = *reinterpret_cast<const short8*>(
                    &Alds[((sub * 288) + mw * 144 + mt * 16 + nlo) * 40 + q * 8]);
                acc[mt][0] = __builtin_amdgcn_mfma_f32_16x16x32_bf16(av, b0, acc[mt][0], 0, 0, 0);
                acc[mt][1] = __builtin_amdgcn_mfma_f32_16x16x32_bf16(av, b1, acc[mt][1], 0, 0, 0);
            }
        }
    };

    // ---- schedule: every vmcnt(0) drain is covered by a full mma phase ----
    loadB(0, 0);       // B0 -> buffer 0
    stageA(0);
    __syncthreads();   // A(0) visible; B0 arrived (prologue-only stall)
    loadB(1, 1);       // B1 -> buffer 1, in flight across mma(0)
    mma(0);            // consumes buffer 0 (B0)
    __syncthreads();   // drains B1 (already landed); A(0) reads done
    stageA(1);
    __syncthreads();   // A(1) visible
    loadB(0, 2);       // B2 -> buffer 0, in flight across mma(1)
    mma(1);            // consumes buffer 1 (B1)
    __syncthreads();   // drains B2 (already landed); A(1) reads done
    stageA(2);
    __syncthreads();   // A(2) visible
    mma(0);            // consumes buffer 0 (B2)  [rounds 2/3 bug: was mma(2)]

    // ---- store: C/D layout col = nlo (t), row = q*4 + r (o) ----
    const int tcol = t0 + tw * 32 + nlo;
#pragma unroll
    for (int mt = 0; mt < 9; ++mt) {
        const int ob = mw * 144 + mt * 16 + q * 4;
#pragma unroll
        for (int nf = 0; nf < 2; ++nf) {
            const int t = tcol + nf * 16;
#pragma unroll
            for (int r = 0; r < 4; ++r) {
                const int o = ob + r;
                if (o < NO) out[((size_t)(b * NO + o)) * NT + t] = acc[mt][nf][r];
            }
        }
    }
}

// ---------------------------------------------------------------------------
extern "C" void kernel_launch(void* const* d_in, const int* in_sizes, int n_in,
                              void* d_out, int out_size, void* d_ws, size_t ws_size,
                              hipStream_t stream) {
    const float* meg = (const float*)d_in[0];       // [32,273,4096] f32
    const float* pos = (const float*)d_in[1];       // [32,273,2] f32
    const int* subj = (const int*)d_in[2];          // [32] i32
    const float* heads = (const float*)d_in[3];     // [200,270,242] f32
    float* out = (float*)d_out;                     // [32,270,4096] f32

    float* emb = (float*)d_ws;                          // 32*273*242 f32 (8.5 MB)
    float* scores = emb + (size_t)NB * NC * ND;         // 32*270*273 f32 (9.4 MB)
    short* wbf = (short*)(scores + (size_t)NB * NO * NC);  // 32*288*288 bf16 (5.3 MB)

    const int emb_items = NB * NC * 121;
    emb_kernel<<<dim3((emb_items + 255) / 256), dim3(256), 0, stream>>>(pos, emb);
    scores_kernel<<<dim3(5, 9, NB), dim3(256), 0, stream>>>(emb, heads, subj, pos, scores);
    softmax_kernel<<<dim3(NB * OPAD), dim3(64), 0, stream>>>(scores, wbf);
    einsum_kernel<<<dim3(NT / TBLK, 1, NB), dim3(256), 0, stream>>>(meg, wbf, out);
}

// Round 5
// 370.238 us; speedup vs baseline: 1.0833x; 1.0065x over previous
//
#include <hip/hip_runtime.h>

// Problem constants
// B=32, C=273, T=4096, CHOUT=270, D=242 (11x11 freqs x {cos,sin})
#define NB 32
#define NC 273
#define NT 4096
#define NO 270
#define ND 242
#define OPAD 272  // padded output-channel count: 17 x 16 frags, >= 270
#define CPAD 288  // padded channel (K) count (multiple of 32, >= 273)
#define TBLK 128  // t columns per einsum block (4 waves x 32 t)
#define NMT 17    // m-fragments (OPAD/16)

typedef __attribute__((ext_vector_type(8))) short short8;
typedef __attribute__((ext_vector_type(4))) float f32x4;

__device__ __forceinline__ short f2bf(float f) {
    union { float f; unsigned int u; } x;
    x.f = f;
    unsigned int r = x.u + 0x7fffu + ((x.u >> 16) & 1u);  // RNE (no NaN/inf in data)
    return (short)(r >> 16);
}

// ---------------------------------------------------------------------------
// Kernel 1: Fourier embedding. emb[b*273+c][242]: cos at [idx], sin at [121+idx]
// ---------------------------------------------------------------------------
__global__ void emb_kernel(const float* __restrict__ pos, float* __restrict__ emb) {
    const int g = blockIdx.x * 256 + threadIdx.x;
    const int TOT = NB * NC * 121;  // 1,057,056
    if (g >= TOT) return;
    const int p = g / 121;
    const int idx = g - p * 121;
    const int fi = idx / 11;
    const int fj = idx - fi * 11;
    const float scale = 4.487989505128276f;  // 2*pi/1.4
    const float px = pos[p * 2] + 0.2f;
    const float py = pos[p * 2 + 1] + 0.2f;
    const float loc = px * (scale * (float)fi) + py * (scale * (float)fj);
    emb[(size_t)p * ND + idx] = cosf(loc);
    emb[(size_t)p * ND + 121 + idx] = sinf(loc);
}

// ---------------------------------------------------------------------------
// Kernel 2: scores[b][o][c] = sum_d heads[subj[b]][o][d]*emb[b][c][d] + offset
// fp32 tiled GEMM, 32x64 tile (grid 1440 = 5.6 blocks/CU, small LDS -> high
// occupancy so staging latency is hidden by TLP). Kchunk=16.
// ---------------------------------------------------------------------------
__global__ __launch_bounds__(256) void scores_kernel(
    const float* __restrict__ emb, const float* __restrict__ heads,
    const int* __restrict__ subj, const float* __restrict__ pos,
    float* __restrict__ scores) {
    __shared__ float As[16 * 36];  // As[k][i] = heads[s][o0+i][kc+k], 32 rows +4 pad
    __shared__ float Bs[16 * 68];  // Bs[k][j] = emb[b][c0+j][kc+k], 64 rows +4 pad
    const int b = blockIdx.z;
    const int o0 = blockIdx.y * 32;
    const int c0 = blockIdx.x * 64;
    const int tid = threadIdx.x;
    const int s = subj[b];
    const int tx = tid & 15, ty = tid >> 4;  // ty 0..15
    const int srow = tid >> 3;  // 0..31
    const int sfp = tid & 7;    // float2 index: cols sfp*2, sfp*2+1

    float acc[2][4] = {};

    for (int kc = 0; kc < 256; kc += 16) {
        const int d = kc + sfp * 2;  // even; ND even -> never a partial pair
        // A: 32 rows x 16 k
        {
            const int o = o0 + srow;
            float2 av = make_float2(0.f, 0.f);
            if (d < ND && o < NO)
                av = *reinterpret_cast<const float2*>(
                    &heads[((size_t)(s * NO + o)) * ND + d]);
            As[(sfp * 2 + 0) * 36 + srow] = av.x;
            As[(sfp * 2 + 1) * 36 + srow] = av.y;
        }
        // B: 64 rows x 16 k
#pragma unroll
        for (int half = 0; half < 2; ++half) {
            const int row = srow + half * 32;
            const int c = c0 + row;
            float2 bv = make_float2(0.f, 0.f);
            if (d < ND && c < NC)
                bv = *reinterpret_cast<const float2*>(
                    &emb[((size_t)(b * NC + c)) * ND + d]);
            Bs[(sfp * 2 + 0) * 68 + row] = bv.x;
            Bs[(sfp * 2 + 1) * 68 + row] = bv.y;
        }
        __syncthreads();
#pragma unroll
        for (int k = 0; k < 16; ++k) {
            const float2 a = *reinterpret_cast<const float2*>(&As[k * 36 + ty * 2]);
            const float4 bvv = *reinterpret_cast<const float4*>(&Bs[k * 68 + tx * 4]);
            const float aa[2] = {a.x, a.y};
            const float bb[4] = {bvv.x, bvv.y, bvv.z, bvv.w};
#pragma unroll
            for (int ii = 0; ii < 2; ++ii)
#pragma unroll
                for (int jj = 0; jj < 4; ++jj) acc[ii][jj] += aa[ii] * bb[jj];
        }
        __syncthreads();
    }

#pragma unroll
    for (int ii = 0; ii < 2; ++ii) {
        const int o = o0 + ty * 2 + ii;
        if (o >= NO) continue;
#pragma unroll
        for (int jj = 0; jj < 4; ++jj) {
            const int c = c0 + tx * 4 + jj;
            if (c >= NC) continue;
            const float px = pos[((size_t)(b * NC + c)) * 2];
            const float py = pos[((size_t)(b * NC + c)) * 2 + 1];
            const float off = (px == -0.1f && py == -0.1f) ? -1e9f : 0.0f;
            scores[((size_t)(b * NO + o)) * NC + c] = acc[ii][jj] + off;
        }
    }
}

// ---------------------------------------------------------------------------
// Kernel 3: softmax over channels (273) -> bf16 weights wbf[b][OPAD][CPAD].
// One wave per (b,o) row. Rows o>=270 and cols c>=273 are zero-filled so the
// einsum can run on the padded 272x288 tile with no masking.
// ---------------------------------------------------------------------------
__global__ __launch_bounds__(64) void softmax_kernel(
    const float* __restrict__ scores, short* __restrict__ wbf) {
    const int row = blockIdx.x;           // b*OPAD + o
    const int b = row / OPAD;
    const int o = row - b * OPAD;
    short* w = wbf + (size_t)row * CPAD;
    const int lane = threadIdx.x;

    if (o >= NO) {  // zero padding rows
        for (int c = lane; c < CPAD; c += 64) w[c] = 0;
        return;
    }

    const float* s = scores + ((size_t)(b * NO + o)) * NC;
    float v[5];
    int cnt = 0;
    float mx = -1e30f;
    for (int c = lane; c < NC; c += 64) {
        v[cnt] = s[c];
        mx = fmaxf(mx, v[cnt]);
        ++cnt;
    }
#pragma unroll
    for (int off = 32; off; off >>= 1) mx = fmaxf(mx, __shfl_xor(mx, off));
    float sum = 0.0f;
    for (int i = 0; i < cnt; ++i) {
        v[i] = expf(v[i] - mx);
        sum += v[i];
    }
#pragma unroll
    for (int off = 32; off; off >>= 1) sum += __shfl_xor(sum, off);
    const float inv = 1.0f / sum;
    int i = 0;
    for (int c = lane; c < CPAD; c += 64) {
        float val = 0.0f;
        if (c < NC) val = v[i++] * inv;
        w[c] = f2bf(val);
    }
}

// ---------------------------------------------------------------------------
// Kernel 4: FUSED transpose+einsum, barrier-free K-loop (round-0-proven
// schedule: A staged ONCE in LDS, depth-3 rolling B register ring, slot=ch%3,
// refill ch+3 — zero barriers after the single stage barrier).
// out[b][o][t] = sum_c w[b][o][c] * meg[b][c][t], bf16 MFMA 16x16x32.
// Block: ALL M=272 (o, padded) x 128 t (4 waves x 32 t) -> meg read from HBM
// exactly once (no megT, no o-tile re-reads). B built in-register from f32
// meg (RNE->bf16). A = full 272x288 bf16 weight tile, fragment-linear in LDS
// (156,672 B -> 1 block/CU; latency hidden by the ring's ILP, the pattern
// the 84us megT kernel already proved at 6.1 TB/s).
// Round-4 lesson: VGPR_Count=108 < the ~190 its schedule needed -> scratch
// spill. Here nothing but acc lives across the single barrier; ring needs
// only 48 VGPRs; __launch_bounds__(256,1) caps at 512 -> no spill.
// ---------------------------------------------------------------------------
__global__ __launch_bounds__(256, 1) void einsum_kernel(
    const float* __restrict__ meg, const short* __restrict__ wbf,
    float* __restrict__ out) {
    __shared__ short Alds[9 * NMT * 64 * 8];  // 156,672 B, fragment-linear
    const int b = blockIdx.z;
    const int t0 = blockIdx.x * TBLK;
    const int tid = threadIdx.x;
    const int l = tid & 63;
    const int tw = tid >> 6;   // wave id 0..3 -> t-cols tw*32 .. tw*32+31
    const int q = l >> 4;      // 0..3
    const int nlo = l & 15;

    f32x4 acc[NMT][2];
#pragma unroll
    for (int i = 0; i < NMT; ++i)
#pragma unroll
        for (int j = 0; j < 2; ++j) acc[i][j] = {0.f, 0.f, 0.f, 0.f};

    const float* mbase = meg + ((size_t)b * NC) * NT + t0 + tw * 32 + nlo;
    const short* wbase = wbf + ((size_t)b * OPAD) * CPAD;

    // B register ring: [slot][j][nf], slot = chunk % 3 (all indices static).
    float Breg[3][8][2];

    // Issue the 16 B dword-loads for K-chunk `ch` into ring slot `slot`.
    // Per instr: 4 c-rows (q) x 16 consecutive t (nlo) = 4 x 64 B segments.
    auto loadB = [&](int slot, int ch) {
#pragma unroll
        for (int j = 0; j < 8; ++j) {
            int c = ch * 32 + q * 8 + j;
            if (c >= NC) c = 0;  // clamp: A rows there are 0, product is 0
            const float* mrow = mbase + (size_t)c * NT;
            Breg[slot][j][0] = mrow[0];
            Breg[slot][j][1] = mrow[16];
        }
    };

    // ---- prologue: B chunks 0..2 in flight, then stage A (overlaps) ----
    loadB(0, 0);
    loadB(1, 1);
    loadB(2, 2);

    // Stage full A [0..271] x [0..287] bf16 -> fragment-linear LDS:
    // Alds[((ch*NMT + mt)*64 + l)*8 + j] = w[mt*16 + (l&15)][ch*32 + (l>>4)*8 + j]
    // Consecutive sidx -> consecutive 16 B in LDS: conflict-free b128 writes.
    for (int sidx = tid; sidx < 9 * NMT * 64; sidx += 256) {
        const int ch = sidx / (NMT * 64);
        const int rem = sidx - ch * (NMT * 64);
        const int mt = rem >> 6;
        const int ll = rem & 63;
        const int row = mt * 16 + (ll & 15);
        const int k = ch * 32 + (ll >> 4) * 8;
        const short8 v = *reinterpret_cast<const short8*>(
            wbase + (size_t)row * CPAD + k);
        *reinterpret_cast<short8*>(&Alds[sidx * 8]) = v;
    }
    __syncthreads();  // one barrier total; drains prologue B (overlapped)

    // ---- K-loop: 9 chunks, NO barriers, rolling refill 3 ahead ----
#pragma unroll
    for (int ch = 0; ch < 9; ++ch) {
        const int slot = ch % 3;  // compile-time under full unroll
        short8 b0, b1;
#pragma unroll
        for (int j = 0; j < 8; ++j) {
            b0[j] = f2bf(Breg[slot][j][0]);
            b1[j] = f2bf(Breg[slot][j][1]);
        }
        if (ch + 3 < 9) loadB(slot, ch + 3);
#pragma unroll
        for (int mt = 0; mt < NMT; ++mt) {
            const short8 av = *reinterpret_cast<const short8*>(
                &Alds[((ch * NMT + mt) * 64 + l) * 8]);
            acc[mt][0] = __builtin_amdgcn_mfma_f32_16x16x32_bf16(av, b0, acc[mt][0], 0, 0, 0);
            acc[mt][1] = __builtin_amdgcn_mfma_f32_16x16x32_bf16(av, b1, acc[mt][1], 0, 0, 0);
        }
    }

    // ---- store: C/D layout col = nlo (t), row = q*4 + r (o) ----
    const int tcol = t0 + tw * 32 + nlo;
#pragma unroll
    for (int mt = 0; mt < NMT; ++mt) {
        const int ob = mt * 16 + q * 4;
#pragma unroll
        for (int nf = 0; nf < 2; ++nf) {
            const int t = tcol + nf * 16;
#pragma unroll
            for (int r = 0; r < 4; ++r) {
                const int o = ob + r;
                if (o < NO) out[((size_t)(b * NO + o)) * NT + t] = acc[mt][nf][r];
            }
        }
    }
}

// ---------------------------------------------------------------------------
extern "C" void kernel_launch(void* const* d_in, const int* in_sizes, int n_in,
                              void* d_out, int out_size, void* d_ws, size_t ws_size,
                              hipStream_t stream) {
    const float* meg = (const float*)d_in[0];       // [32,273,4096] f32
    const float* pos = (const float*)d_in[1];       // [32,273,2] f32
    const int* subj = (const int*)d_in[2];          // [32] i32
    const float* heads = (const float*)d_in[3];     // [200,270,242] f32
    float* out = (float*)d_out;                     // [32,270,4096] f32

    float* emb = (float*)d_ws;                          // 32*273*242 f32 (8.5 MB)
    float* scores = emb + (size_t)NB * NC * ND;         // 32*270*273 f32 (9.4 MB)
    short* wbf = (short*)(scores + (size_t)NB * NO * NC);  // 32*272*288 bf16 (5.0 MB)

    const int emb_items = NB * NC * 121;
    emb_kernel<<<dim3((emb_items + 255) / 256), dim3(256), 0, stream>>>(pos, emb);
    scores_kernel<<<dim3(5, 9, NB), dim3(256), 0, stream>>>(emb, heads, subj, pos, scores);
    softmax_kernel<<<dim3(NB * OPAD), dim3(64), 0, stream>>>(scores, wbf);
    einsum_kernel<<<dim3(NT / TBLK, 1, NB), dim3(256), 0, stream>>>(meg, wbf, out);
}

// Round 6
// 334.313 us; speedup vs baseline: 1.1997x; 1.1075x over previous
//
#include <hip/hip_runtime.h>

// Problem constants
// B=32, C=273, T=4096, CHOUT=270, D=242 (11x11 freqs x {cos,sin})
#define NB 32
#define NC 273
#define NT 4096
#define NO 270
#define ND 242
#define OPAD 272  // padded output-channel count: 17 x 16 frags, >= 270
#define CPAD 288  // padded channel (K) count (multiple of 32, >= 273)
#define TBLK 256  // t columns per einsum block (8 waves x 32 t)
#define NMT 17    // m-fragments (OPAD/16)

typedef __attribute__((ext_vector_type(8))) short short8;
typedef __attribute__((ext_vector_type(4))) float f32x4;

__device__ __forceinline__ short f2bf(float f) {
    union { float f; unsigned int u; } x;
    x.f = f;
    unsigned int r = x.u + 0x7fffu + ((x.u >> 16) & 1u);  // RNE (no NaN/inf in data)
    return (short)(r >> 16);
}

// ---------------------------------------------------------------------------
// Kernel 1: Fourier embedding. emb[b*273+c][242]: cos at [idx], sin at [121+idx]
// ---------------------------------------------------------------------------
__global__ void emb_kernel(const float* __restrict__ pos, float* __restrict__ emb) {
    const int g = blockIdx.x * 256 + threadIdx.x;
    const int TOT = NB * NC * 121;  // 1,057,056
    if (g >= TOT) return;
    const int p = g / 121;
    const int idx = g - p * 121;
    const int fi = idx / 11;
    const int fj = idx - fi * 11;
    const float scale = 4.487989505128276f;  // 2*pi/1.4
    const float px = pos[p * 2] + 0.2f;
    const float py = pos[p * 2 + 1] + 0.2f;
    const float loc = px * (scale * (float)fi) + py * (scale * (float)fj);
    emb[(size_t)p * ND + idx] = cosf(loc);
    emb[(size_t)p * ND + 121 + idx] = sinf(loc);
}

// ---------------------------------------------------------------------------
// Kernel 2: scores[b][o][c] = sum_d heads[subj[b]][o][d]*emb[b][c][d] + offset
// fp32 tiled GEMM, 32x64 tile (grid 1440 = 5.6 blocks/CU, small LDS -> high
// occupancy so staging latency is hidden by TLP). Kchunk=16.
// ---------------------------------------------------------------------------
__global__ __launch_bounds__(256) void scores_kernel(
    const float* __restrict__ emb, const float* __restrict__ heads,
    const int* __restrict__ subj, const float* __restrict__ pos,
    float* __restrict__ scores) {
    __shared__ float As[16 * 36];  // As[k][i] = heads[s][o0+i][kc+k], 32 rows +4 pad
    __shared__ float Bs[16 * 68];  // Bs[k][j] = emb[b][c0+j][kc+k], 64 rows +4 pad
    const int b = blockIdx.z;
    const int o0 = blockIdx.y * 32;
    const int c0 = blockIdx.x * 64;
    const int tid = threadIdx.x;
    const int s = subj[b];
    const int tx = tid & 15, ty = tid >> 4;  // ty 0..15
    const int srow = tid >> 3;  // 0..31
    const int sfp = tid & 7;    // float2 index: cols sfp*2, sfp*2+1

    float acc[2][4] = {};

    for (int kc = 0; kc < 256; kc += 16) {
        const int d = kc + sfp * 2;  // even; ND even -> never a partial pair
        // A: 32 rows x 16 k
        {
            const int o = o0 + srow;
            float2 av = make_float2(0.f, 0.f);
            if (d < ND && o < NO)
                av = *reinterpret_cast<const float2*>(
                    &heads[((size_t)(s * NO + o)) * ND + d]);
            As[(sfp * 2 + 0) * 36 + srow] = av.x;
            As[(sfp * 2 + 1) * 36 + srow] = av.y;
        }
        // B: 64 rows x 16 k
#pragma unroll
        for (int half = 0; half < 2; ++half) {
            const int row = srow + half * 32;
            const int c = c0 + row;
            float2 bv = make_float2(0.f, 0.f);
            if (d < ND && c < NC)
                bv = *reinterpret_cast<const float2*>(
                    &emb[((size_t)(b * NC + c)) * ND + d]);
            Bs[(sfp * 2 + 0) * 68 + row] = bv.x;
            Bs[(sfp * 2 + 1) * 68 + row] = bv.y;
        }
        __syncthreads();
#pragma unroll
        for (int k = 0; k < 16; ++k) {
            const float2 a = *reinterpret_cast<const float2*>(&As[k * 36 + ty * 2]);
            const float4 bvv = *reinterpret_cast<const float4*>(&Bs[k * 68 + tx * 4]);
            const float aa[2] = {a.x, a.y};
            const float bb[4] = {bvv.x, bvv.y, bvv.z, bvv.w};
#pragma unroll
            for (int ii = 0; ii < 2; ++ii)
#pragma unroll
                for (int jj = 0; jj < 4; ++jj) acc[ii][jj] += aa[ii] * bb[jj];
        }
        __syncthreads();
    }

#pragma unroll
    for (int ii = 0; ii < 2; ++ii) {
        const int o = o0 + ty * 2 + ii;
        if (o >= NO) continue;
#pragma unroll
        for (int jj = 0; jj < 4; ++jj) {
            const int c = c0 + tx * 4 + jj;
            if (c >= NC) continue;
            const float px = pos[((size_t)(b * NC + c)) * 2];
            const float py = pos[((size_t)(b * NC + c)) * 2 + 1];
            const float off = (px == -0.1f && py == -0.1f) ? -1e9f : 0.0f;
            scores[((size_t)(b * NO + o)) * NC + c] = acc[ii][jj] + off;
        }
    }
}

// ---------------------------------------------------------------------------
// Kernel 3: softmax over channels (273) -> bf16 weights wbf[b][OPAD][CPAD].
// One wave per (b,o) row. Rows o>=270 and cols c>=273 are zero-filled so the
// einsum can run on the padded 272x288 tile with no masking.
// ---------------------------------------------------------------------------
__global__ __launch_bounds__(64) void softmax_kernel(
    const float* __restrict__ scores, short* __restrict__ wbf) {
    const int row = blockIdx.x;           // b*OPAD + o
    const int b = row / OPAD;
    const int o = row - b * OPAD;
    short* w = wbf + (size_t)row * CPAD;
    const int lane = threadIdx.x;

    if (o >= NO) {  // zero padding rows
        for (int c = lane; c < CPAD; c += 64) w[c] = 0;
        return;
    }

    const float* s = scores + ((size_t)(b * NO + o)) * NC;
    float v[5];
    int cnt = 0;
    float mx = -1e30f;
    for (int c = lane; c < NC; c += 64) {
        v[cnt] = s[c];
        mx = fmaxf(mx, v[cnt]);
        ++cnt;
    }
#pragma unroll
    for (int off = 32; off; off >>= 1) mx = fmaxf(mx, __shfl_xor(mx, off));
    float sum = 0.0f;
    for (int i = 0; i < cnt; ++i) {
        v[i] = expf(v[i] - mx);
        sum += v[i];
    }
#pragma unroll
    for (int off = 32; off; off >>= 1) sum += __shfl_xor(sum, off);
    const float inv = 1.0f / sum;
    int i = 0;
    for (int c = lane; c < CPAD; c += 64) {
        float val = 0.0f;
        if (c < NC) val = v[i++] * inv;
        w[c] = f2bf(val);
    }
}

// ---------------------------------------------------------------------------
// Kernel 4: FUSED transpose+einsum, barrier-free K-loop.
// out[b][o][t] = sum_c w[b][o][c] * meg[b][c][t], bf16 MFMA 16x16x32.
// Round-5 post-mortem: traffic near-ideal (FETCH 90MB, WRITE 138MB, 0 bank
// conflicts) but 1 block/CU x 4 waves = 1 wave/SIMD -> latency-bound
// (MfmaUtil 6%, VALU 9%, Occ 11%; 31.5us/block vs 11us BW floor).
// This round: SAME schedule (A staged once in LDS, depth-3 B register ring,
// one barrier total), but 512 threads / 8 waves, TBLK=256:
//   - 2 waves/SIMD (2x TLP for every exposed latency)
//   - 2 sequential blocks/CU instead of 4 (half the prologue/tail dead time)
//   - staging prologue explicitly batched (5 loads, then 5 ds_writes)
// Traffic unchanged: meg read exactly once. VGPR ~215 < 256 cap at
// __launch_bounds__(512,2) -> no spill (round-4 lesson).
// ---------------------------------------------------------------------------
__global__ __launch_bounds__(512, 2) void einsum_kernel(
    const float* __restrict__ meg, const short* __restrict__ wbf,
    float* __restrict__ out) {
    __shared__ short Alds[9 * NMT * 64 * 8];  // 156,672 B, fragment-linear
    const int b = blockIdx.z;
    const int t0 = blockIdx.x * TBLK;
    const int tid = threadIdx.x;
    const int l = tid & 63;
    const int tw = tid >> 6;   // wave id 0..7 -> t-cols tw*32 .. tw*32+31
    const int q = l >> 4;      // 0..3
    const int nlo = l & 15;

    f32x4 acc[NMT][2];
#pragma unroll
    for (int i = 0; i < NMT; ++i)
#pragma unroll
        for (int j = 0; j < 2; ++j) acc[i][j] = {0.f, 0.f, 0.f, 0.f};

    const float* mbase = meg + ((size_t)b * NC) * NT + t0 + tw * 32 + nlo;
    const short* wbase = wbf + ((size_t)b * OPAD) * CPAD;

    // B register ring: [slot][j][nf], slot = chunk % 3 (all indices static).
    float Breg[3][8][2];

    // Issue the 16 B dword-loads for K-chunk `ch` into ring slot `slot`.
    // Per instr: 4 c-rows (q) x 16 consecutive t (nlo) = 4 x 64 B segments.
    auto loadB = [&](int slot, int ch) {
#pragma unroll
        for (int j = 0; j < 8; ++j) {
            int c = ch * 32 + q * 8 + j;
            if (c >= NC) c = 0;  // clamp: A rows there are 0, product is 0
            const float* mrow = mbase + (size_t)c * NT;
            Breg[slot][j][0] = mrow[0];
            Breg[slot][j][1] = mrow[16];
        }
    };

    // ---- prologue: B chunks 0..2 in flight, then stage A (overlaps) ----
    loadB(0, 0);
    loadB(1, 1);
    loadB(2, 2);

    // Stage full A [0..271] x [0..287] bf16 -> fragment-linear LDS:
    // Alds[((ch*NMT + mt)*64 + ll)*8 + j] = w[mt*16 + (ll&15)][ch*32 + (ll>>4)*8 + j]
    // Batched: 5 independent global loads, then 5 ds_writes (pipelined, vs a
    // serial load->write->load chain). Consecutive sidx -> consecutive 16 B.
    const int ATOT = 9 * NMT * 64;  // 9792 16-B segments
    for (int base = 0; base < ATOT; base += 512 * 5) {
        short8 tmp[5];
#pragma unroll
        for (int u = 0; u < 5; ++u) {
            const int sidx = base + u * 512 + tid;
            if (sidx < ATOT) {
                const int ch = sidx / (NMT * 64);
                const int rem = sidx - ch * (NMT * 64);
                const int mt = rem >> 6;
                const int ll = rem & 63;
                const int row = mt * 16 + (ll & 15);
                const int k = ch * 32 + (ll >> 4) * 8;
                tmp[u] = *reinterpret_cast<const short8*>(
                    wbase + (size_t)row * CPAD + k);
            }
        }
#pragma unroll
        for (int u = 0; u < 5; ++u) {
            const int sidx = base + u * 512 + tid;
            if (sidx < ATOT)
                *reinterpret_cast<short8*>(&Alds[sidx * 8]) = tmp[u];
        }
    }
    __syncthreads();  // one barrier total; drains prologue B (overlapped)

    // ---- K-loop: 9 chunks, NO barriers, rolling refill 3 ahead ----
#pragma unroll
    for (int ch = 0; ch < 9; ++ch) {
        const int slot = ch % 3;  // compile-time under full unroll
        short8 b0, b1;
#pragma unroll
        for (int j = 0; j < 8; ++j) {
            b0[j] = f2bf(Breg[slot][j][0]);
            b1[j] = f2bf(Breg[slot][j][1]);
        }
        if (ch + 3 < 9) loadB(slot, ch + 3);
#pragma unroll
        for (int mt = 0; mt < NMT; ++mt) {
            const short8 av = *reinterpret_cast<const short8*>(
                &Alds[((ch * NMT + mt) * 64 + l) * 8]);
            acc[mt][0] = __builtin_amdgcn_mfma_f32_16x16x32_bf16(av, b0, acc[mt][0], 0, 0, 0);
            acc[mt][1] = __builtin_amdgcn_mfma_f32_16x16x32_bf16(av, b1, acc[mt][1], 0, 0, 0);
        }
    }

    // ---- store: C/D layout col = nlo (t), row = q*4 + r (o) ----
    const int tcol = t0 + tw * 32 + nlo;
#pragma unroll
    for (int mt = 0; mt < NMT; ++mt) {
        const int ob = mt * 16 + q * 4;
#pragma unroll
        for (int nf = 0; nf < 2; ++nf) {
            const int t = tcol + nf * 16;
#pragma unroll
            for (int r = 0; r < 4; ++r) {
                const int o = ob + r;
                if (o < NO) out[((size_t)(b * NO + o)) * NT + t] = acc[mt][nf][r];
            }
        }
    }
}

// ---------------------------------------------------------------------------
extern "C" void kernel_launch(void* const* d_in, const int* in_sizes, int n_in,
                              void* d_out, int out_size, void* d_ws, size_t ws_size,
                              hipStream_t stream) {
    const float* meg = (const float*)d_in[0];       // [32,273,4096] f32
    const float* pos = (const float*)d_in[1];       // [32,273,2] f32
    const int* subj = (const int*)d_in[2];          // [32] i32
    const float* heads = (const float*)d_in[3];     // [200,270,242] f32
    float* out = (float*)d_out;                     // [32,270,4096] f32

    float* emb = (float*)d_ws;                          // 32*273*242 f32 (8.5 MB)
    float* scores = emb + (size_t)NB * NC * ND;         // 32*270*273 f32 (9.4 MB)
    short* wbf = (short*)(scores + (size_t)NB * NO * NC);  // 32*272*288 bf16 (5.0 MB)

    const int emb_items = NB * NC * 121;
    emb_kernel<<<dim3((emb_items + 255) / 256), dim3(256), 0, stream>>>(pos, emb);
    scores_kernel<<<dim3(5, 9, NB), dim3(256), 0, stream>>>(emb, heads, subj, pos, scores);
    softmax_kernel<<<dim3(NB * OPAD), dim3(64), 0, stream>>>(scores, wbf);
    einsum_kernel<<<dim3(NT / TBLK, 1, NB), dim3(512), 0, stream>>>(meg, wbf, out);
}